// Round 9
// baseline (387.371 us; speedup 1.0000x reference)
//
#include <hip/hip_runtime.h>
#include <math.h>

// ---------------------------------------------------------------------------
// Sinkhorn ETP (FASTopic) on MI355X.
// n=256 topics, m=32768 words, D=384.
//
//   log_K0[i,j] = G[i,j] + su0[i] + sv0[j],  G = 40 * x@y^T
//   Per iteration:  L1[j] = lse_i(G+su);  W[j] = log_b - L1[j]
//                   L2[i] = lse_j(G+W);   su'[i] = log_a - L2[i]
//   Final: transp[i,j] = exp(G+su[i]+W[j]); M = nx[i]+ny[j]-0.05*G;
//          loss = sum(transp*M)
//
// R9: top-K truncation. R7/R8 showed the iteration floor is G-read BW
// (32 MB/iter from L3 ~ 2.9 us). Per column, entries >32 nats below the
// column max of A=G+su contribute < e^-32 (invisible in fp32). After iter 1
// row marginals are exactly balanced (no starved rows), su drift is small,
// so a per-column top-K (threshold 32 nats, cap 32, keyed at su1) carries
// the whole trajectory: 5.25 MB/iter instead of 32 MB. Iter 1 stays full
// log-safe; colerr + finalize use full G.
// ---------------------------------------------------------------------------

#define N_TOPIC 256
#define N_WORD  32768

static constexpr float LOG_A = -5.545177444479562f;    // log(1/256 + 1e-30)
static constexpr float LOG_B = -10.397207708399179f;   // log(1/32768 + 1e-30)
static constexpr float BVAL  = 3.0517578125e-05f;      // 1/32768

typedef float f32x4 __attribute__((ext_vector_type(4)));
typedef short bf16x8 __attribute__((ext_vector_type(8)));

// ---------------------------------------------------------------- init ------
__global__ __launch_bounds__(256) void init_k(
    const float* __restrict__ x, const float* __restrict__ y,
    float* __restrict__ nx, float* __restrict__ ny, float* __restrict__ su,
    unsigned* __restrict__ colerr, int* __restrict__ active,
    int* __restrict__ counters, float* __restrict__ out)
{
    const int b = blockIdx.x, t = threadIdx.x;
    const int w = t >> 6, l = t & 63;
    if (b < 8192) {                       // ||y_j||^2, 4 rows/block (wave per row)
        const int r = (b << 2) + w;
        const float4* y4 = (const float4*)y;
        float4 v = y4[r * 96 + l];
        float s = v.x * v.x + v.y * v.y + v.z * v.z + v.w * v.w;
        if (l < 32) {
            float4 u = y4[r * 96 + 64 + l];
            s += u.x * u.x + u.y * u.y + u.z * u.z + u.w * u.w;
        }
        for (int off = 32; off; off >>= 1) s += __shfl_down(s, off);
        if (l == 0) ny[r] = s;
    } else if (b < 8256) {                // ||x_i||^2 and su0 = -20*nx
        const int r = ((b - 8192) << 2) + w;
        const float4* x4 = (const float4*)x;
        float4 v = x4[r * 96 + l];
        float s = v.x * v.x + v.y * v.y + v.z * v.z + v.w * v.w;
        if (l < 32) {
            float4 u = x4[r * 96 + 64 + l];
            s += u.x * u.x + u.y * u.y + u.z * u.z + u.w * u.w;
        }
        for (int off = 32; off; off >>= 1) s += __shfl_down(s, off);
        if (l == 0) { nx[r] = s; su[r] = -20.f * s; }
    } else {
        for (int k = t; k < 4096; k += 256) counters[k] = 0;
        if (t == 0) { colerr[0] = 0u; colerr[1] = 0u; active[0] = 1; out[0] = 0.f; }
    }
}

// ---------------------------------------------------------------- gemm ------
// Exact 3-way bf16 truncation split: v = b0 + b1 + b2 (+ r3, |r3|<=2^-27|v|).
static __device__ __forceinline__ void split3(float v, ushort& h0, ushort& h1, ushort& h2)
{
    unsigned u0 = __float_as_uint(v);
    h0 = (ushort)(u0 >> 16);
    float r1 = v - __uint_as_float(u0 & 0xFFFF0000u);
    unsigned u1 = __float_as_uint(r1);
    h1 = (ushort)(u1 >> 16);
    float r2 = r1 - __uint_as_float(u1 & 0xFFFF0000u);
    h2 = (ushort)(__float_as_uint(r2) >> 16);
}

// Block tile 128i x 128j, K-chunks of 32, grid (256 jb, 2 ib) = 512 blocks.
__global__ __launch_bounds__(256, 1) void gemm_k(
    const float* __restrict__ x, const float* __restrict__ y, float* __restrict__ G)
{
    __shared__ __align__(16) ushort xs0[5120], xs1[5120], xs2[5120];
    __shared__ __align__(16) ushort ys0[5120], ys1[5120], ys2[5120];

    const int t   = threadIdx.x;
    const int jb  = blockIdx.x << 7;   // 128-col slab
    const int ib  = blockIdx.y << 7;   // 128-row slab
    const int w   = t >> 6;            // wave 0..3
    const int ln  = t & 63;
    const int q   = ln >> 4;           // quad 0..3
    const int l15 = ln & 15;

    const float4* x4 = (const float4*)x;
    const float4* y4 = (const float4*)y;

    f32x4 acc[2][8];
#pragma unroll
    for (int mi = 0; mi < 2; ++mi)
#pragma unroll
        for (int nj = 0; nj < 8; ++nj) acc[mi][nj] = (f32x4){0.f, 0.f, 0.f, 0.f};

    for (int kc = 0; kc < 12; ++kc) {
        __syncthreads();
#pragma unroll
        for (int p = 0; p < 4; ++p) {
            const int f  = (t << 2) + p;       // 0..1023 float4 slots
            const int r  = f >> 3, c4 = f & 7; // row, k-quad
            const int o  = r * 40 + (c4 << 2);
            float4 vx = x4[(ib + r) * 96 + (kc << 3) + c4];
            ushort a0,a1,a2,b0,b1,b2,c0,c1,c2,d0,d1,d2;
            split3(vx.x, a0,a1,a2); split3(vx.y, b0,b1,b2);
            split3(vx.z, c0,c1,c2); split3(vx.w, d0,d1,d2);
            *(ushort4*)&xs0[o] = make_ushort4(a0,b0,c0,d0);
            *(ushort4*)&xs1[o] = make_ushort4(a1,b1,c1,d1);
            *(ushort4*)&xs2[o] = make_ushort4(a2,b2,c2,d2);
            float4 vy = y4[(jb + r) * 96 + (kc << 3) + c4];
            split3(vy.x, a0,a1,a2); split3(vy.y, b0,b1,b2);
            split3(vy.z, c0,c1,c2); split3(vy.w, d0,d1,d2);
            *(ushort4*)&ys0[o] = make_ushort4(a0,b0,c0,d0);
            *(ushort4*)&ys1[o] = make_ushort4(a1,b1,c1,d1);
            *(ushort4*)&ys2[o] = make_ushort4(a2,b2,c2,d2);
        }
        __syncthreads();

        bf16x8 A[3][2];
#pragma unroll
        for (int mi = 0; mi < 2; ++mi) {
            const int off = ((w << 5) + (mi << 4) + l15) * 40 + (q << 3);
            A[0][mi] = *(const bf16x8*)&xs0[off];
            A[1][mi] = *(const bf16x8*)&xs1[off];
            A[2][mi] = *(const bf16x8*)&xs2[off];
        }
#pragma unroll
        for (int nj = 0; nj < 8; ++nj) {
            const int off = ((nj << 4) + l15) * 40 + (q << 3);
            bf16x8 B0 = *(const bf16x8*)&ys0[off];
            bf16x8 B1 = *(const bf16x8*)&ys1[off];
            bf16x8 B2 = *(const bf16x8*)&ys2[off];
#pragma unroll
            for (int mi = 0; mi < 2; ++mi) {
                f32x4 c = acc[mi][nj];
                c = __builtin_amdgcn_mfma_f32_16x16x32_bf16(A[0][mi], B0, c, 0, 0, 0);
                c = __builtin_amdgcn_mfma_f32_16x16x32_bf16(A[0][mi], B1, c, 0, 0, 0);
                c = __builtin_amdgcn_mfma_f32_16x16x32_bf16(A[1][mi], B0, c, 0, 0, 0);
                c = __builtin_amdgcn_mfma_f32_16x16x32_bf16(A[1][mi], B1, c, 0, 0, 0);
                c = __builtin_amdgcn_mfma_f32_16x16x32_bf16(A[0][mi], B2, c, 0, 0, 0);
                c = __builtin_amdgcn_mfma_f32_16x16x32_bf16(A[2][mi], B0, c, 0, 0, 0);
                acc[mi][nj] = c;
            }
        }
    }
#pragma unroll
    for (int mi = 0; mi < 2; ++mi) {
        const int gi0 = ib + (w << 5) + (mi << 4) + (q << 2);
#pragma unroll
        for (int nj = 0; nj < 8; ++nj) {
            const int gj = jb + (nj << 4) + l15;
#pragma unroll
            for (int r = 0; r < 4; ++r)
                G[(size_t)(gi0 + r) * 32768 + gj] = 40.f * acc[mi][nj][r];
        }
    }
}

// -------------------------------------------- iteration (safe, iter 1) ------
__global__ __launch_bounds__(256) void sink_step(
    const float* __restrict__ G, float* __restrict__ su,
    float* __restrict__ W, float2* __restrict__ pms, float2* __restrict__ lms,
    int* __restrict__ cnt, const int* __restrict__ active, int gated)
{
    if (gated && active[0] == 0) return;
    __shared__ float comb[1024];
    __shared__ float Mlds[64];
    __shared__ float Wlds[64];
    __shared__ float m_arr[256 * 17];
    __shared__ float s_arr[256 * 17];
    __shared__ int lastf;

    const int t  = threadIdx.x;
    const int b  = blockIdx.x;
    const int j0 = b << 6;
    const int jq = t & 15;
    const int is = t >> 4;

    const float4* G4 = (const float4*)G;
    float4 tile[16];
    float  sur[16];
#pragma unroll
    for (int k = 0; k < 16; ++k) {
        int i = is + (k << 4);
        tile[k] = G4[i * 8192 + (j0 >> 2) + jq];
        sur[k]  = su[i];
    }

    float m0 = -INFINITY, m1 = -INFINITY, m2 = -INFINITY, m3 = -INFINITY;
#pragma unroll
    for (int k = 0; k < 16; ++k) {
        m0 = fmaxf(m0, tile[k].x + sur[k]);
        m1 = fmaxf(m1, tile[k].y + sur[k]);
        m2 = fmaxf(m2, tile[k].z + sur[k]);
        m3 = fmaxf(m3, tile[k].w + sur[k]);
    }
    ((float4*)comb)[(is << 4) + jq] = make_float4(m0, m1, m2, m3);
    __syncthreads();
    if (t < 64) {
        float m = -INFINITY;
#pragma unroll
        for (int s = 0; s < 16; ++s) m = fmaxf(m, comb[(s << 6) + t]);
        Mlds[t] = m;
    }
    __syncthreads();
    float4 Mq = make_float4(Mlds[4 * jq + 0], Mlds[4 * jq + 1],
                            Mlds[4 * jq + 2], Mlds[4 * jq + 3]);
    float s0 = 0.f, s1 = 0.f, s2 = 0.f, s3 = 0.f;
#pragma unroll
    for (int k = 0; k < 16; ++k) {
        s0 += __expf(tile[k].x + sur[k] - Mq.x);
        s1 += __expf(tile[k].y + sur[k] - Mq.y);
        s2 += __expf(tile[k].z + sur[k] - Mq.z);
        s3 += __expf(tile[k].w + sur[k] - Mq.w);
    }
    ((float4*)comb)[(is << 4) + jq] = make_float4(s0, s1, s2, s3);
    __syncthreads();
    if (t < 64) {
        float ssum = 0.f;
#pragma unroll
        for (int s = 0; s < 16; ++s) ssum += comb[(s << 6) + t];
        float Wj = LOG_B - (Mlds[t] + __logf(ssum));
        Wlds[t] = Wj;
        W[j0 + t] = Wj;
    }
    __syncthreads();
    float4 Wq = make_float4(Wlds[4 * jq + 0], Wlds[4 * jq + 1],
                            Wlds[4 * jq + 2], Wlds[4 * jq + 3]);

#pragma unroll
    for (int k = 0; k < 16; ++k) {
        float a0 = tile[k].x + Wq.x;
        float a1 = tile[k].y + Wq.y;
        float a2 = tile[k].z + Wq.z;
        float a3 = tile[k].w + Wq.w;
        float m = fmaxf(fmaxf(a0, a1), fmaxf(a2, a3));
        float s = __expf(a0 - m) + __expf(a1 - m) + __expf(a2 - m) + __expf(a3 - m);
        int i = is + (k << 4);
        m_arr[i * 17 + jq] = m;
        s_arr[i * 17 + jq] = s;
    }
    __syncthreads();
    {
        float m = -INFINITY, s = 0.f;
#pragma unroll
        for (int p = 0; p < 16; ++p) {
            float pmv = m_arr[t * 17 + p];
            float psv = s_arr[t * 17 + p];
            float nm = fmaxf(m, pmv);
            s = s * __expf(m - nm) + psv * __expf(pmv - nm);
            m = nm;
        }
        pms[(b << 8) + t] = make_float2(m, s);
    }

    __threadfence();
    if (t == 0) lastf = (atomicAdd(cnt + (b >> 4), 1) == 15);
    __syncthreads();
    if (!lastf) return;
    __threadfence();

    const int g = b >> 4;
    {
        float cm[4] = {-INFINITY, -INFINITY, -INFINITY, -INFINITY};
        float cs[4] = {0.f, 0.f, 0.f, 0.f};
#pragma unroll
        for (int p = 0; p < 16; p += 4) {
#pragma unroll
            for (int c = 0; c < 4; ++c) {
                float2 v = pms[(((g << 4) + p + c) << 8) + t];
                float nm = fmaxf(cm[c], v.x);
                cs[c] = cs[c] * __expf(cm[c] - nm) + v.y * __expf(v.x - nm);
                cm[c] = nm;
            }
        }
        float m = cm[0], s = cs[0];
#pragma unroll
        for (int c = 1; c < 4; ++c) {
            float nm = fmaxf(m, cm[c]);
            s = s * __expf(m - nm) + cs[c] * __expf(cm[c] - nm);
            m = nm;
        }
        lms[(g << 8) + t] = make_float2(m, s);
    }

    __threadfence();
    if (t == 0) lastf = (atomicAdd(cnt + 32, 1) == 31);
    __syncthreads();
    if (!lastf) return;
    __threadfence();

    {
        float cm[4] = {-INFINITY, -INFINITY, -INFINITY, -INFINITY};
        float cs[4] = {0.f, 0.f, 0.f, 0.f};
#pragma unroll
        for (int p = 0; p < 32; p += 4) {
#pragma unroll
            for (int c = 0; c < 4; ++c) {
                float2 v = lms[((p + c) << 8) + t];
                float nm = fmaxf(cm[c], v.x);
                cs[c] = cs[c] * __expf(cm[c] - nm) + v.y * __expf(v.x - nm);
                cm[c] = nm;
            }
        }
        float m = cm[0], s = cs[0];
#pragma unroll
        for (int c = 1; c < 4; ++c) {
            float nm = fmaxf(m, cm[c]);
            s = s * __expf(m - nm) + cs[c] * __expf(cm[c] - nm);
            m = nm;
        }
        su[t] = LOG_A - (m + __logf(s));
    }
}

// ------------------------------------------------------- top-K build --------
// After iter 1 (su = su1): per column keep entries with G+su >= colmax-32,
// cap 32. vals[j*32+e] = raw G (su re-added each iter); rows packed 4/uint.
__global__ __launch_bounds__(256) void build_k(
    const float* __restrict__ G, const float* __restrict__ su,
    float* __restrict__ vals, unsigned* __restrict__ rowsp)
{
    __shared__ float comb[1024];
    __shared__ float Mlds[64];
    __shared__ float lv[2048];
    __shared__ unsigned char lr[2048];
    __shared__ int ccnt[64];

    const int t  = threadIdx.x;
    const int b  = blockIdx.x;
    const int j0 = b << 6;
    const int jq = t & 15;
    const int is = t >> 4;

    const float4* G4 = (const float4*)G;
    float4 tile[16];
    float  sur[16];
#pragma unroll
    for (int k = 0; k < 16; ++k) {
        int i = is + (k << 4);
        tile[k] = G4[i * 8192 + (j0 >> 2) + jq];
        sur[k]  = su[i];
    }
    float m0 = -INFINITY, m1 = -INFINITY, m2 = -INFINITY, m3 = -INFINITY;
#pragma unroll
    for (int k = 0; k < 16; ++k) {
        m0 = fmaxf(m0, tile[k].x + sur[k]);
        m1 = fmaxf(m1, tile[k].y + sur[k]);
        m2 = fmaxf(m2, tile[k].z + sur[k]);
        m3 = fmaxf(m3, tile[k].w + sur[k]);
    }
    ((float4*)comb)[(is << 4) + jq] = make_float4(m0, m1, m2, m3);
    __syncthreads();
    if (t < 64) {
        float m = -INFINITY;
#pragma unroll
        for (int s = 0; s < 16; ++s) m = fmaxf(m, comb[(s << 6) + t]);
        Mlds[t] = m;
        ccnt[t] = 0;
    }
    __syncthreads();
    float4 Mq = make_float4(Mlds[4 * jq + 0] - 32.f, Mlds[4 * jq + 1] - 32.f,
                            Mlds[4 * jq + 2] - 32.f, Mlds[4 * jq + 3] - 32.f);
#pragma unroll
    for (int k = 0; k < 16; ++k) {
        const int i = is + (k << 4);
        if (tile[k].x + sur[k] >= Mq.x) {
            int s = atomicAdd(&ccnt[4 * jq + 0], 1);
            if (s < 32) { lv[(4 * jq + 0) * 32 + s] = tile[k].x; lr[(4 * jq + 0) * 32 + s] = (unsigned char)i; }
        }
        if (tile[k].y + sur[k] >= Mq.y) {
            int s = atomicAdd(&ccnt[4 * jq + 1], 1);
            if (s < 32) { lv[(4 * jq + 1) * 32 + s] = tile[k].y; lr[(4 * jq + 1) * 32 + s] = (unsigned char)i; }
        }
        if (tile[k].z + sur[k] >= Mq.z) {
            int s = atomicAdd(&ccnt[4 * jq + 2], 1);
            if (s < 32) { lv[(4 * jq + 2) * 32 + s] = tile[k].z; lr[(4 * jq + 2) * 32 + s] = (unsigned char)i; }
        }
        if (tile[k].w + sur[k] >= Mq.w) {
            int s = atomicAdd(&ccnt[4 * jq + 3], 1);
            if (s < 32) { lv[(4 * jq + 3) * 32 + s] = tile[k].w; lr[(4 * jq + 3) * 32 + s] = (unsigned char)i; }
        }
    }
    __syncthreads();
    for (int s = t; s < 2048; s += 256) {
        const int c = s >> 5, e = s & 31;
        const int cn = min(ccnt[c], 32);
        vals[((size_t)(j0 + c) << 5) + e] = (e < cn) ? lv[s] : -1e30f;
    }
    for (int s = t; s < 512; s += 256) {
        const int c = s >> 3, q = s & 7;
        const int cn = min(ccnt[c], 32);
        unsigned pk = 0;
#pragma unroll
        for (int z = 0; z < 4; ++z) {
            const int e = (q << 2) + z;
            unsigned r = (e < cn) ? (unsigned)lr[(c << 5) + e] : 0u;
            pk |= r << (z << 3);
        }
        rowsp[((j0 + c) << 3) + q] = pk;
    }
}

// ------------------------------------------- iteration (top-K, 2..100) ------
// 128 blocks x 256 thr; thread t owns column j = b*256+t (32 entries).
// Row accumulation via LDS float atomics; two-level tree (8 groups of 16).
__global__ __launch_bounds__(256) void sink_topk(
    const float* __restrict__ vals, const unsigned* __restrict__ rowsp,
    float* __restrict__ su, float* __restrict__ W,
    float* __restrict__ prow, float* __restrict__ lrow,
    int* __restrict__ cnt, const int* __restrict__ active)
{
    if (active[0] == 0) return;
    __shared__ float su_lds[256];
    __shared__ float rowacc[256];
    __shared__ int lastf;

    const int t = threadIdx.x, b = blockIdx.x;
    const int j = (b << 8) + t;

    su_lds[t] = su[t];
    rowacc[t] = 0.f;
    __syncthreads();

    const float4* v4 = (const float4*)(vals + ((size_t)j << 5));
    const uint4*  r4 = ((const uint4*)rowsp) + (j << 1);
    uint4 rA = r4[0], rB = r4[1];
    unsigned rw[8] = {rA.x, rA.y, rA.z, rA.w, rB.x, rB.y, rB.z, rB.w};

    float a[32];
    float M = -INFINITY;
#pragma unroll
    for (int q = 0; q < 8; ++q) {
        float4 v = v4[q];
        unsigned r = rw[q];
        a[4 * q + 0] = v.x + su_lds[r & 255];
        a[4 * q + 1] = v.y + su_lds[(r >> 8) & 255];
        a[4 * q + 2] = v.z + su_lds[(r >> 16) & 255];
        a[4 * q + 3] = v.w + su_lds[r >> 24];
        M = fmaxf(M, fmaxf(fmaxf(a[4 * q + 0], a[4 * q + 1]),
                           fmaxf(a[4 * q + 2], a[4 * q + 3])));
    }
    float S = 0.f;
#pragma unroll
    for (int e = 0; e < 32; ++e) { a[e] = __expf(a[e] - M); S += a[e]; }
    const float inv = 1.0f / S;
    W[j] = LOG_B - (M + __logf(S));
#pragma unroll
    for (int q = 0; q < 8; ++q) {
        unsigned r = rw[q];
        atomicAdd(&rowacc[r & 255],         a[4 * q + 0] * inv);
        atomicAdd(&rowacc[(r >> 8) & 255],  a[4 * q + 1] * inv);
        atomicAdd(&rowacc[(r >> 16) & 255], a[4 * q + 2] * inv);
        atomicAdd(&rowacc[r >> 24],         a[4 * q + 3] * inv);
    }
    __syncthreads();
    prow[(b << 8) + t] = rowacc[t];

    // two-level plain-sum combine (row sums >= a*b: no log-domain needed)
    __threadfence();
    if (t == 0) lastf = (atomicAdd(cnt + (b >> 4), 1) == 15);
    __syncthreads();
    if (!lastf) return;
    __threadfence();

    const int g = b >> 4;
    {
        float acc = 0.f;
#pragma unroll
        for (int p = 0; p < 16; ++p) acc += prow[(((g << 4) + p) << 8) + t];
        lrow[(g << 8) + t] = acc;
    }
    __threadfence();
    if (t == 0) lastf = (atomicAdd(cnt + 8, 1) == 7);
    __syncthreads();
    if (!lastf) return;
    __threadfence();
    {
        float tot = 0.f;
#pragma unroll
        for (int p = 0; p < 8; ++p) tot += lrow[(p << 8) + t];
        su[t] = (LOG_A - LOG_B) + su_lds[t] - __logf(tot);
    }
}

// --------------------------------------------- absorb-step column error -----
__global__ __launch_bounds__(256) void sink_colerr(
    const float* __restrict__ G, const float* __restrict__ su,
    const float* __restrict__ W, unsigned* __restrict__ colerr, int slot,
    int* __restrict__ counter, int* __restrict__ active, int gated)
{
    if (gated && active[0] == 0) return;
    __shared__ float comb[1024];
    __shared__ float Mlds[64];

    const int t  = threadIdx.x;
    const int b  = blockIdx.x;
    const int j0 = b << 6;
    const int jq = t & 15;
    const int is = t >> 4;

    const float4* G4 = (const float4*)G;
    float4 tile[16];
    float  sur[16];
#pragma unroll
    for (int k = 0; k < 16; ++k) {
        int i = is + (k << 4);
        tile[k] = G4[i * 8192 + (j0 >> 2) + jq];
        sur[k]  = su[i];
    }
    float m0 = -INFINITY, m1 = -INFINITY, m2 = -INFINITY, m3 = -INFINITY;
#pragma unroll
    for (int k = 0; k < 16; ++k) {
        m0 = fmaxf(m0, tile[k].x + sur[k]);
        m1 = fmaxf(m1, tile[k].y + sur[k]);
        m2 = fmaxf(m2, tile[k].z + sur[k]);
        m3 = fmaxf(m3, tile[k].w + sur[k]);
    }
    ((float4*)comb)[(is << 4) + jq] = make_float4(m0, m1, m2, m3);
    __syncthreads();
    if (t < 64) {
        float m = -INFINITY;
#pragma unroll
        for (int s = 0; s < 16; ++s) m = fmaxf(m, comb[(s << 6) + t]);
        Mlds[t] = m;
    }
    __syncthreads();
    float4 Mq = make_float4(Mlds[4 * jq + 0], Mlds[4 * jq + 1],
                            Mlds[4 * jq + 2], Mlds[4 * jq + 3]);
    float s0 = 0.f, s1 = 0.f, s2 = 0.f, s3 = 0.f;
#pragma unroll
    for (int k = 0; k < 16; ++k) {
        s0 += __expf(tile[k].x + sur[k] - Mq.x);
        s1 += __expf(tile[k].y + sur[k] - Mq.y);
        s2 += __expf(tile[k].z + sur[k] - Mq.z);
        s3 += __expf(tile[k].w + sur[k] - Mq.w);
    }
    ((float4*)comb)[(is << 4) + jq] = make_float4(s0, s1, s2, s3);
    __syncthreads();
    if (t < 64) {
        float ssum = 0.f;
#pragma unroll
        for (int s = 0; s < 16; ++s) ssum += comb[(s << 6) + t];
        float Aj  = Mlds[t] + __logf(ssum);
        float col = __expf(Aj + W[j0 + t]);
        float d   = fabsf(col - BVAL);
        for (int off = 32; off; off >>= 1) d = fmaxf(d, __shfl_down(d, off));
        if (t == 0) {
            atomicMax(colerr + slot, __float_as_uint(d));
            __threadfence();
            if (atomicAdd(counter, 1) == 511) {
                __threadfence();
                unsigned e = atomicMax(colerr + slot, 0u);
                active[0] = (__uint_as_float(e) > 0.005f) ? 1 : 0;
            }
        }
    }
}

// ------------------------------------------------------------- finalize -----
__global__ __launch_bounds__(256) void finalize_k(
    const float* __restrict__ G, const float* __restrict__ su,
    const float* __restrict__ W, const float* __restrict__ nx,
    const float* __restrict__ ny, float* __restrict__ out)
{
    __shared__ float su_lds[256], nx_lds[256];
    __shared__ float red[4];
    const int t = threadIdx.x, b = blockIdx.x;
    const int j0 = b << 7;
    const int jq = t & 31;
    const int ig = t >> 5;
    su_lds[t] = su[t];
    nx_lds[t] = nx[t];
    __syncthreads();

    const float4* G4 = (const float4*)G;
    const float4 Wq  = ((const float4*)W)[(j0 >> 2) + jq];
    const float4 nyq = ((const float4*)ny)[(j0 >> 2) + jq];
    const int jbase = 1 + j0 + (jq << 2);
    float acc = 0.f;
#pragma unroll 4
    for (int it = 0; it < 32; ++it) {
        const int i = ig + (it << 3);
        float4 g = G4[i * 8192 + (j0 >> 2) + jq];
        const float si = su_lds[i], nxi = nx_lds[i];
        float v0 = __expf(g.x + si + Wq.x);
        float v1 = __expf(g.y + si + Wq.y);
        float v2 = __expf(g.z + si + Wq.z);
        float v3 = __expf(g.w + si + Wq.w);
        float* o = out + jbase + (size_t)i * 32768;
        o[0] = v0; o[1] = v1; o[2] = v2; o[3] = v3;
        acc += v0 * (nxi + nyq.x - 0.05f * g.x) +
               v1 * (nxi + nyq.y - 0.05f * g.y) +
               v2 * (nxi + nyq.z - 0.05f * g.z) +
               v3 * (nxi + nyq.w - 0.05f * g.w);
    }
    for (int off = 32; off; off >>= 1) acc += __shfl_down(acc, off);
    if ((t & 63) == 0) red[t >> 6] = acc;
    __syncthreads();
    if (t == 0) atomicAdd(out, red[0] + red[1] + red[2] + red[3]);
}

// ---------------------------------------------------------------- host ------
extern "C" void kernel_launch(void* const* d_in, const int* in_sizes, int n_in,
                              void* d_out, int out_size, void* d_ws, size_t ws_size,
                              hipStream_t stream)
{
    const float* x = (const float*)d_in[0];   // [256, 384]
    const float* y = (const float*)d_in[1];   // [32768, 384]
    float* out = (float*)d_out;               // [1 + 256*32768]

    float* ws   = (float*)d_ws;
    float* G    = ws;                 // 8388608
    float* Wv   = G + 8388608;        // 32768
    float* su   = Wv + 32768;         // 256
    float* nx   = su + 256;           // 256
    float* ny   = nx + 256;           // 32768
    float2* pms = (float2*)(ny + 32768);           // 131072 float2 (iter 1)
    float2* lms = pms + 131072;                    // 8192 float2
    float* prow = (float*)(lms + 8192);            // 32768 (topk iters)
    float* lrow = prow + 32768;                    // 2048
    float* vals = lrow + 2048;                     // 1048576 (topK values)
    unsigned* rowsp = (unsigned*)(vals + 1048576); // 262144 (packed rows)
    unsigned* colerr = rowsp + 262144;             // 2
    int* active   = (int*)(colerr + 2);            // 1
    int* counters = active + 1;                    // 4096

    init_k<<<8257, 256, 0, stream>>>(x, y, nx, ny, su, colerr, active, counters, out);
    gemm_k<<<dim3(256, 2), 256, 0, stream>>>(x, y, G);

    // iteration 1 (log-safe, full G) + absorb error check
    sink_step<<<512, 256, 0, stream>>>(G, su, Wv, pms, lms, counters + 0, active, 0);
    sink_colerr<<<512, 256, 0, stream>>>(G, su, Wv, colerr, 0, counters + 4000, active, 0);

    // build per-column top-K keyed at su1
    build_k<<<512, 256, 0, stream>>>(G, su, vals, rowsp);

    for (int tt = 2; tt <= 100; ++tt) {
        sink_topk<<<128, 256, 0, stream>>>(vals, rowsp, su, Wv, prow, lrow,
                                           counters + 16 * (tt - 1), active);
        if (tt == 51)   // absorb at cpt_n=51: error check gates the rest
            sink_colerr<<<512, 256, 0, stream>>>(G, su, Wv, colerr, 1,
                                                 counters + 4001, active, 1);
    }

    finalize_k<<<256, 256, 0, stream>>>(G, su, Wv, nx, ny, out);
}